// Round 14
// baseline (464.569 us; speedup 1.0000x reference)
//
#include <hip/hip_runtime.h>
#include <hip/hip_bf16.h>

// MultimodalFusion: B*H=16384 tokens, NMOD=4, M=512, NH=8, DH=64, FFN=2048.
// R14: x4 eliminated. pack = weights only; K1 keeps R13 structure but stages A
// by reg from fp32 inputs (float4x2+cvt -> swizzled ds_write); B stays gl_lds.
// K2 residual = fp32 xs gather (R5 form). Everything else R13.
//
// ws layout (bytes):
//   wqkv_b  @ 0          1,572,864   (1536x512 bf16)
//   wout_b  @ 1572864      524,288   (512x512)
//   w1_b    @ 2097152    2,097,152   (2048x512)
//   w2_b    @ 4194304    2,097,152   (512x2048)
//   ffn2s   @ 6291456   33,554,432   (16384x512 fp32, used after K4)
//   o_buf   @ 73400320  67,108,864   (bf16)  [hidden overlays after K2]
//   agg_f   @ 140509184 33,554,432   (16384x512 fp32)
//   agg_b   @ 174063616 16,777,216   (16384x512 bf16)

typedef __attribute__((ext_vector_type(8))) short s16x8;
typedef __attribute__((ext_vector_type(4))) float f32x4;

__device__ __forceinline__ unsigned short f2bf(float f) {
  unsigned int u = __float_as_uint(f);
  u += 0x7fffu + ((u >> 16) & 1u);
  return (unsigned short)(u >> 16);
}
__device__ __forceinline__ float bf2f(unsigned short s) {
  return __uint_as_float(((unsigned int)s) << 16);
}
__device__ __forceinline__ f32x4 mfma16(s16x8 a, s16x8 b, f32x4 c) {
  return __builtin_amdgcn_mfma_f32_16x16x32_bf16(a, b, c, 0, 0, 0);
}
// byte offset into a [rows][64] bf16 tile (128B rows), XOR-swizzled 16B granules
__device__ __forceinline__ int swz(int row, int bir) {
  return row * 128 + ((((row) & 7) << 4) ^ bir);
}
// scalar u16 element in a [rows][64] swizzled tile
__device__ __forceinline__ int qkswz(int row, int c) {
  return row * 128 + ((((c >> 3) ^ (row & 7)) << 4)) + (c & 7) * 2;
}
// Vt [64][128] u16: row=d (256B), col=token-row; XOR key d&7
__device__ __forceinline__ int vtswz(int d, int row) {
  return d * 256 + ((((row >> 3) ^ (d & 7)) << 4)) + (row & 7) * 2;
}
// Pw [128][32] u16: 64B rows; XOR key row&3
__device__ __forceinline__ int pwswz(int row, int c) {
  return row * 64 + ((((c >> 3) ^ (row & 3)) << 4)) + (c & 7) * 2;
}
// byte offset into a [rows][512] bf16 vt tile (1024B rows), XOR-swizzled
__device__ __forceinline__ int vtoff(int r, int c) {
  return r * 1024 + ((c * 2) ^ ((r & 7) << 4));
}
// async global->LDS 16B per lane; dest = wave-uniform base + lane*16
__device__ __forceinline__ void gl_lds16(const void* g, void* l) {
  __builtin_amdgcn_global_load_lds(
      (const __attribute__((address_space(1))) unsigned int*)g,
      (__attribute__((address_space(3))) unsigned int*)l, 16, 0, 0);
}

// ---------------------------------------------------------------- pack (weights only)
__global__ void pack_w_kernel(const float* __restrict__ wqkv, const float* __restrict__ wout,
                              const float* __restrict__ w1, const float* __restrict__ w2,
                              unsigned short* __restrict__ o_wqkv, unsigned short* __restrict__ o_wout,
                              unsigned short* __restrict__ o_w1, unsigned short* __restrict__ o_w2) {
  const long c0 = 196608, c1 = 262144, c2 = 524288, c3 = 786432;
  for (long v = (long)blockIdx.x * blockDim.x + threadIdx.x; v < c3;
       v += (long)gridDim.x * blockDim.x) {
    const float* src;
    unsigned short* dst;
    if (v < c0) { src = wqkv + v * 4; dst = o_wqkv + v * 4; }
    else if (v < c1) { long u = v - c0; src = wout + u * 4; dst = o_wout + u * 4; }
    else if (v < c2) { long u = v - c1; src = w1 + u * 4; dst = o_w1 + u * 4; }
    else { long u = v - c2; src = w2 + u * 4; dst = o_w2 + u * 4; }
    float4 f = *reinterpret_cast<const float4*>(src);
    ushort4 hb;
    hb.x = f2bf(f.x); hb.y = f2bf(f.y); hb.z = f2bf(f.z); hb.w = f2bf(f.w);
    *reinterpret_cast<ushort4*>(dst) = hb;
  }
}

// ---------------------------------------------------------------- K1: qkv + attention
// flat grid 4096; XCD-bijective swizzle. A staged by reg from fp32 xs
// (float4x2 + cvt -> swizzled ds_write); B staged via gl_lds (linear dest,
// pre-swizzled source). LDS 49152: @0 aT/Qs/Pw, @16384 bT/Ks/outT, @32768 Vt.
__launch_bounds__(256, 3)
__global__ void qkv_attn_kernel(const float* __restrict__ x0, const float* __restrict__ x1,
                                const float* __restrict__ x2, const float* __restrict__ x3,
                                const unsigned short* __restrict__ wqkv,
                                const float* __restrict__ in_b,
                                unsigned short* __restrict__ o_out) {
  const int wg = blockIdx.x;
  const int slot = wg >> 3, xcd = wg & 7;
  const int tb = ((slot >> 3) << 3) | xcd;  // [0,512)
  const int h = slot & 7;                   // [0,8)
  const int tid = threadIdx.x, lane = tid & 63, w = tid >> 6;
  const int wm = w >> 1, wn = w & 1;

  __shared__ __align__(16) unsigned char smem[49152];
  unsigned short* aT = (unsigned short*)smem;            // [128][64] staging
  unsigned short* bT = (unsigned short*)(smem + 16384);  // [192][64] staging
  unsigned short* Qs = (unsigned short*)smem;            // [128][64] (over aT)
  unsigned short* Ks = (unsigned short*)(smem + 16384);  // [128][64] (over bT head)
  unsigned short* Vt = (unsigned short*)(smem + 32768);  // [64][128] (over bT tail)
  unsigned short* Pw = (unsigned short*)smem;            // [128][32] (over Qs, after sacc)
  unsigned short* outT = (unsigned short*)(smem + 16384);// [128][64] qkswz (over Ks, after sacc)

  f32x4 acc[4][6];
#pragma unroll
  for (int i = 0; i < 4; ++i)
#pragma unroll
    for (int j = 0; j < 6; ++j) acc[i][j] = (f32x4){0.f, 0.f, 0.f, 0.f};

  const long rowBase = (long)tb * 128;
  const long tokBase = (long)tb * 32;  // 128 rows = 32 tokens
  const int loff = ((lane >> 3) * 512) + (((lane & 7) ^ (lane >> 3)) * 8);
  const float* xs[4] = {x0, x1, x2, x3};

  for (int kk = 0; kk < 8; ++kk) {
    const int k0 = kk * 64;
#pragma unroll
    for (int it = 0; it < 6; ++it) {  // B: 24 chunks of 8 weight rows (gl_lds)
      int c = w * 6 + it;
      int bc0 = c * 8;
      int wb = (bc0 < 64) ? (h * 64 + bc0)
             : (bc0 < 128) ? (512 + h * 64 + (bc0 - 64))
                           : (1024 + h * 64 + (bc0 - 128));
      gl_lds16(wqkv + (long)wb * 512 + k0 + loff, bT + c * 512);
    }
#pragma unroll
    for (int it = 0; it < 4; ++it) {  // A: 128 rows x 8 chunks, reg from fp32
      int cid = tid + it * 256, lr = cid >> 3, c8 = cid & 7;
      int s = lr & 3;
      long n = tokBase + (lr >> 2);
      const float* src = xs[s] + n * 512 + k0 + c8 * 8;
      float4 f0 = *(const float4*)src;
      float4 f1 = *(const float4*)(src + 4);
      s16x8 v;
      v[0] = (short)f2bf(f0.x); v[1] = (short)f2bf(f0.y);
      v[2] = (short)f2bf(f0.z); v[3] = (short)f2bf(f0.w);
      v[4] = (short)f2bf(f1.x); v[5] = (short)f2bf(f1.y);
      v[6] = (short)f2bf(f1.z); v[7] = (short)f2bf(f1.w);
      *(s16x8*)((unsigned char*)aT + swz(lr, c8 * 16)) = v;
    }
    __syncthreads();
#pragma unroll
    for (int k2 = 0; k2 < 2; ++k2) {
      s16x8 af[4], bfr[6];
      const int bir = k2 * 64 + ((lane >> 4) << 4);
#pragma unroll
      for (int mi = 0; mi < 4; ++mi) {
        int row = wm * 64 + mi * 16 + (lane & 15);
        af[mi] = *(const s16x8*)((unsigned char*)aT + swz(row, bir));
      }
#pragma unroll
      for (int ni = 0; ni < 6; ++ni) {
        int col = wn * 96 + ni * 16 + (lane & 15);
        bfr[ni] = *(const s16x8*)((unsigned char*)bT + swz(col, bir));
      }
#pragma unroll
      for (int mi = 0; mi < 4; ++mi)
#pragma unroll
        for (int ni = 0; ni < 6; ++ni)
          acc[mi][ni] = mfma16(af[mi], bfr[ni], acc[mi][ni]);
    }
    __syncthreads();
  }

  // epilogue: acc(+bias) -> Qs / Ks / Vt (bf16).  D: col=lane&15, row=(lane>>4)*4+r
#pragma unroll
  for (int mi = 0; mi < 4; ++mi)
#pragma unroll
    for (int ni = 0; ni < 6; ++ni) {
      int col = wn * 96 + ni * 16 + (lane & 15);
      int wb = (col < 64) ? (h * 64 + col)
             : (col < 128) ? (512 + h * 64 + (col - 64))
                           : (1024 + h * 64 + (col - 128));
      float bias = in_b[wb];
      int row0 = wm * 64 + mi * 16 + ((lane >> 4) << 2);
#pragma unroll
      for (int r = 0; r < 4; ++r) {
        int row = row0 + r;
        unsigned short hv = f2bf(acc[mi][ni][r] + bias);
        if (col < 64)
          *(unsigned short*)((unsigned char*)Qs + qkswz(row, col)) = hv;
        else if (col < 128)
          *(unsigned short*)((unsigned char*)Ks + qkswz(row, col - 64)) = hv;
        else
          *(unsigned short*)((unsigned char*)Vt + vtswz(col - 128, row)) = hv;
      }
    }
  __syncthreads();

  // S = Q.K^T per 16-row tile (2 tiles/wave), MFMA
  f32x4 sacc[2];
#pragma unroll
  for (int i2 = 0; i2 < 2; ++i2) {
    int ti = w * 2 + i2;
    int qrow = ti * 16 + (lane & 15);
    int bir = (lane >> 4) << 4;
    s16x8 qa0 = *(const s16x8*)((unsigned char*)Qs + swz(qrow, bir));
    s16x8 qa1 = *(const s16x8*)((unsigned char*)Qs + swz(qrow, 64 + bir));
    s16x8 ka0 = *(const s16x8*)((unsigned char*)Ks + swz(qrow, bir));
    s16x8 ka1 = *(const s16x8*)((unsigned char*)Ks + swz(qrow, 64 + bir));
    f32x4 s = (f32x4){0.f, 0.f, 0.f, 0.f};
    s = mfma16(qa0, ka0, s);
    s = mfma16(qa1, ka1, s);
    sacc[i2] = s;
  }
  __syncthreads();  // Qs/Ks dead; Pw and outT may now overlay them
  {
    s16x8 z = (s16x8){0, 0, 0, 0, 0, 0, 0, 0};
    ((s16x8*)Pw)[tid] = z;
    ((s16x8*)Pw)[tid + 256] = z;
  }
  __syncthreads();

  // softmax: lane holds S[qrow=(ti*16+(l>>4)*4+r)][kcol=ti*16+(l&15)].
  const bool rel = ((lane & 15) >> 2) == (lane >> 4);
#pragma unroll
  for (int i2 = 0; i2 < 2; ++i2) {
    int ti = w * 2 + i2;
#pragma unroll
    for (int r = 0; r < 4; ++r) {
      float sc = sacc[i2][r] * 0.125f;
      float m = fmaxf(sc, __shfl_xor(sc, 1));
      m = fmaxf(m, __shfl_xor(m, 2));
      float e = __expf(sc - m);
      float su = e + __shfl_xor(e, 1);
      su = su + __shfl_xor(su, 2);
      float p = e / su;
      if (rel) {
        int row = ti * 16 + ((lane >> 4) << 2) + r;
        int cl = (((row >> 2) & 7) << 2) + (lane & 3);
        *(unsigned short*)((unsigned char*)Pw + pwswz(row, cl)) = f2bf(p);
      }
    }
  }
  __syncthreads();

  // PV per tile: o(16x64) = Pw(16x32 window) x Vt; 4 MFMA, write outT
#pragma unroll
  for (int i2 = 0; i2 < 2; ++i2) {
    int ti = w * 2 + i2;
    int arow = ti * 16 + (lane & 15);
    s16x8 pa = *(const s16x8*)((unsigned char*)Pw + arow * 64 +
                               ((((lane >> 4) ^ (arow & 3)) << 4)));
    f32x4 pv4[4];
#pragma unroll
    for (int n = 0; n < 4; ++n) {
      int d = n * 16 + (lane & 15);
      int gran = ((ti >> 1) << 2) + (lane >> 4);
      s16x8 vb = *(const s16x8*)((unsigned char*)Vt + d * 256 +
                                 (((gran ^ (d & 7)) << 4)));
      pv4[n] = mfma16(pa, vb, (f32x4){0.f, 0.f, 0.f, 0.f});
    }
#pragma unroll
    for (int n = 0; n < 4; ++n) {
      int d = n * 16 + (lane & 15);
      int row0 = ti * 16 + ((lane >> 4) << 2);
#pragma unroll
      for (int r = 0; r < 4; ++r)
        *(unsigned short*)((unsigned char*)outT + qkswz(row0 + r, d)) =
            f2bf(pv4[n][r]);
    }
  }
  __syncthreads();
#pragma unroll
  for (int j = 0; j < 4; ++j) {
    int c = j * 256 + tid;
    int row = c >> 3, ch = c & 7;
    s16x8 v = *(const s16x8*)((unsigned char*)outT + qkswz(row, ch * 8));
    *(s16x8*)(o_out + (rowBase + row) * 512 + h * 64 + ch * 8) = v;
  }
}

// ---------------------------------------------------------------- K2: out_proj + LN1 + agg
// grid 2048 (8 tokens = 32 X-rows each). Residual F from fp32 xs (R5 form).
__launch_bounds__(256)
__global__ void outproj_ln1_kernel(const unsigned short* __restrict__ o_in,
                                   const unsigned short* __restrict__ wout,
                                   const float* __restrict__ out_b,
                                   const float* __restrict__ x0, const float* __restrict__ x1,
                                   const float* __restrict__ x2, const float* __restrict__ x3,
                                   const float* __restrict__ ln1_g, const float* __restrict__ ln1_b,
                                   float* __restrict__ agg_f, unsigned short* __restrict__ agg_b) {
  const int tb = blockIdx.x;
  const int tid = threadIdx.x, lane = tid & 63, w = tid >> 6;
  __shared__ __align__(16) unsigned char smem[53504];
  unsigned short* vt = (unsigned short*)smem;            // [32][512] bf16, XOR-swizzled
  unsigned short* aT = (unsigned short*)(smem + 32768);  // [32][64]
  unsigned short* bT = (unsigned short*)(smem + 36864);  // [128][64]
  float* stats = (float*)(smem + 53248);                 // [32][2]
  const long rowBase = (long)tb * 32;
  const float* xs[4] = {x0, x1, x2, x3};

  for (int ns = 0; ns < 4; ++ns) {
    f32x4 acc[2][2];
#pragma unroll
    for (int i = 0; i < 2; ++i)
#pragma unroll
      for (int j = 0; j < 2; ++j) acc[i][j] = (f32x4){0.f, 0.f, 0.f, 0.f};
    for (int kk = 0; kk < 8; ++kk) {
      const int k0 = kk * 64;
      {
        int lr = tid >> 3, c8 = tid & 7;
        s16x8 v = *(const s16x8*)(o_in + (rowBase + lr) * 512 + k0 + c8 * 8);
        *(s16x8*)((unsigned char*)aT + swz(lr, c8 * 16)) = v;
      }
#pragma unroll
      for (int it = 0; it < 4; ++it) {
        int cid = tid + it * 256, bc = cid >> 3, c8 = cid & 7;
        s16x8 v = *(const s16x8*)(wout + (long)(ns * 128 + bc) * 512 + k0 + c8 * 8);
        *(s16x8*)((unsigned char*)bT + swz(bc, c8 * 16)) = v;
      }
      __syncthreads();
#pragma unroll
      for (int k2 = 0; k2 < 2; ++k2) {
        s16x8 af[2], bfr[2];
        const int bir = k2 * 64 + ((lane >> 4) << 4);
#pragma unroll
        for (int mi = 0; mi < 2; ++mi) {
          int row = mi * 16 + (lane & 15);
          af[mi] = *(const s16x8*)((unsigned char*)aT + swz(row, bir));
        }
#pragma unroll
        for (int ni = 0; ni < 2; ++ni) {
          int col = w * 32 + ni * 16 + (lane & 15);
          bfr[ni] = *(const s16x8*)((unsigned char*)bT + swz(col, bir));
        }
#pragma unroll
        for (int mi = 0; mi < 2; ++mi)
#pragma unroll
          for (int ni = 0; ni < 2; ++ni)
            acc[mi][ni] = mfma16(af[mi], bfr[ni], acc[mi][ni]);
      }
      __syncthreads();
    }
#pragma unroll
    for (int mi = 0; mi < 2; ++mi)
#pragma unroll
      for (int ni = 0; ni < 2; ++ni) {
        int gcol = ns * 128 + w * 32 + ni * 16 + (lane & 15);
        float bias = out_b[gcol];
        int row0 = mi * 16 + ((lane >> 4) << 2);
#pragma unroll
        for (int r = 0; r < 4; ++r) {
          int rr = row0 + r;
          long grow = rowBase + rr;
          int s = (int)(grow & 3); long n = grow >> 2;
          float F = xs[s][n * 512 + gcol];
          *(unsigned short*)((unsigned char*)vt + vtoff(rr, gcol)) =
              f2bf(acc[mi][ni][r] + bias + F);
        }
      }
  }
  __syncthreads();
  {  // per-row LN1 stats: one wave per 8 rows
    int wv = tid >> 6, ln = tid & 63;
    for (int i = 0; i < 8; ++i) {
      int r = wv * 8 + i;
      s16x8 v8 = *(const s16x8*)((unsigned char*)vt + vtoff(r, ln * 8));
      float sum = 0.f, sq = 0.f;
#pragma unroll
      for (int d = 0; d < 8; ++d) {
        float v = bf2f((unsigned short)v8[d]);
        sum += v; sq += v * v;
      }
#pragma unroll
      for (int off = 1; off < 64; off <<= 1) {
        sum += __shfl_xor(sum, off); sq += __shfl_xor(sq, off);
      }
      if (ln == 0) {
        float mu = sum * (1.f / 512.f);
        float var = sq * (1.f / 512.f) - mu * mu;
        stats[r * 2] = mu;
        stats[r * 2 + 1] = rsqrtf(var + 1e-5f);
      }
    }
  }
  __syncthreads();
  for (int it = 0; it < 2; ++it) {  // agg over modalities, 8-col chunks
    int ci = tid + it * 256;
    int tok = ci >> 6, c0 = (ci & 63) * 8;
    long gtok = (long)tb * 8 + tok;
    float a[8] = {0.f, 0.f, 0.f, 0.f, 0.f, 0.f, 0.f, 0.f};
#pragma unroll
    for (int s = 0; s < 4; ++s) {
      int r = tok * 4 + s;
      s16x8 v8 = *(const s16x8*)((unsigned char*)vt + vtoff(r, c0));
      float mu = stats[r * 2], is = stats[r * 2 + 1];
#pragma unroll
      for (int d = 0; d < 8; ++d) a[d] += (bf2f((unsigned short)v8[d]) - mu) * is;
    }
    float4 g0 = *(const float4*)(ln1_g + c0);
    float4 g1 = *(const float4*)(ln1_g + c0 + 4);
    float4 b0 = *(const float4*)(ln1_b + c0);
    float4 b1 = *(const float4*)(ln1_b + c0 + 4);
    float ov[8];
    ov[0] = g0.x * a[0] + 4.f * b0.x; ov[1] = g0.y * a[1] + 4.f * b0.y;
    ov[2] = g0.z * a[2] + 4.f * b0.z; ov[3] = g0.w * a[3] + 4.f * b0.w;
    ov[4] = g1.x * a[4] + 4.f * b1.x; ov[5] = g1.y * a[5] + 4.f * b1.y;
    ov[6] = g1.z * a[6] + 4.f * b1.z; ov[7] = g1.w * a[7] + 4.f * b1.w;
    *(float4*)(agg_f + gtok * 512 + c0) = (float4){ov[0], ov[1], ov[2], ov[3]};
    *(float4*)(agg_f + gtok * 512 + c0 + 4) = (float4){ov[4], ov[5], ov[6], ov[7]};
    s16x8 ab;
#pragma unroll
    for (int d = 0; d < 8; ++d) ab[d] = (short)f2bf(ov[d]);
    *(s16x8*)(agg_b + gtok * 512 + c0) = ab;
  }
}

// ---------------------------------------------------------------- K3: ffn1 + gelu
__launch_bounds__(256)
__global__ void ffn1_kernel(const unsigned short* __restrict__ aggb,
                            const unsigned short* __restrict__ w1b,
                            const float* __restrict__ b1,
                            unsigned short* __restrict__ hidden) {
  const int wg = blockIdx.x;
  const int slot = wg >> 3, xcd = wg & 7;
  const int by = ((slot >> 4) << 3) | xcd;  // [0,128) row-tile
  const int bx = slot & 15;                 // [0,16)  col-tile
  const int tid = threadIdx.x, lane = tid & 63, w = tid >> 6;
  const int wm = w >> 1, wn = w & 1;
  __shared__ __align__(16) unsigned char smem[32768];
  unsigned short* aT = (unsigned short*)smem;            // [128][64]
  unsigned short* bT = (unsigned short*)(smem + 16384);  // [128][64]
  f32x4 acc[4][4];
#pragma unroll
  for (int i = 0; i < 4; ++i)
#pragma unroll
    for (int j = 0; j < 4; ++j) acc[i][j] = (f32x4){0.f, 0.f, 0.f, 0.f};
  const long rowBase = (long)by * 128;
  const long colBase = (long)bx * 128;
  const int loff = ((lane >> 3) * 512) + (((lane & 7) ^ (lane >> 3)) * 8);
  for (int kk = 0; kk < 8; ++kk) {
    const int k0 = kk * 64;
#pragma unroll
    for (int it = 0; it < 4; ++it) {
      int c = w * 4 + it;
      gl_lds16(aggb + (rowBase + c * 8) * 512 + k0 + loff, aT + c * 512);
    }
#pragma unroll
    for (int it = 0; it < 4; ++it) {
      int c = w * 4 + it;
      gl_lds16(w1b + (colBase + c * 8) * 512 + k0 + loff, bT + c * 512);
    }
    __syncthreads();
#pragma unroll
    for (int k2 = 0; k2 < 2; ++k2) {
      s16x8 af[4], bfr[4];
      const int bir = k2 * 64 + ((lane >> 4) << 4);
#pragma unroll
      for (int mi = 0; mi < 4; ++mi) {
        int row = wm * 64 + mi * 16 + (lane & 15);
        af[mi] = *(const s16x8*)((unsigned char*)aT + swz(row, bir));
      }
#pragma unroll
      for (int ni = 0; ni < 4; ++ni) {
        int col = wn * 64 + ni * 16 + (lane & 15);
        bfr[ni] = *(const s16x8*)((unsigned char*)bT + swz(col, bir));
      }
#pragma unroll
      for (int mi = 0; mi < 4; ++mi)
#pragma unroll
        for (int ni = 0; ni < 4; ++ni)
          acc[mi][ni] = mfma16(af[mi], bfr[ni], acc[mi][ni]);
    }
    __syncthreads();
  }
#pragma unroll
  for (int mi = 0; mi < 4; ++mi)
#pragma unroll
    for (int ni = 0; ni < 4; ++ni) {
      long gcol = colBase + wn * 64 + ni * 16 + (lane & 15);
      float bias = b1[gcol];
      int row0 = wm * 64 + mi * 16 + ((lane >> 4) << 2);
#pragma unroll
      for (int r = 0; r < 4; ++r) {
        float x = acc[mi][ni][r] + bias;
        float g = 0.5f * x * (1.f + erff(x * 0.70710678118f));
        hidden[(rowBase + row0 + r) * 2048 + gcol] = f2bf(g);
      }
    }
}

// ---------------------------------------------------------------- K4: ffn2 GEMM
__launch_bounds__(256)
__global__ void ffn2_kernel(const unsigned short* __restrict__ hidden,
                            const unsigned short* __restrict__ w2b,
                            const float* __restrict__ b2,
                            const float* __restrict__ agg_f,
                            float* __restrict__ ffn2s) {
  const int wg = blockIdx.x;
  const int slot = wg >> 3, xcd = wg & 7;
  const int by = ((slot >> 2) << 3) | xcd;  // [0,128) row-tile
  const int bx = slot & 3;                  // [0,4)   col-tile
  const int tid = threadIdx.x, lane = tid & 63, w = tid >> 6;
  const int wm = w >> 1, wn = w & 1;
  __shared__ __align__(16) unsigned char smem[32768];
  unsigned short* aT = (unsigned short*)smem;            // [128][64]
  unsigned short* bT = (unsigned short*)(smem + 16384);  // [128][64]
  f32x4 acc[4][4];
#pragma unroll
  for (int i = 0; i < 4; ++i)
#pragma unroll
    for (int j = 0; j < 4; ++j) acc[i][j] = (f32x4){0.f, 0.f, 0.f, 0.f};
  const long rowBase = (long)by * 128;
  const long colBase = (long)bx * 128;
  const int loff2k = ((lane >> 3) * 2048) + (((lane & 7) ^ (lane >> 3)) * 8);
  for (int kk = 0; kk < 32; ++kk) {
    const int k0 = kk * 64;
#pragma unroll
    for (int it = 0; it < 4; ++it) {
      int c = w * 4 + it;
      gl_lds16(hidden + (rowBase + c * 8) * 2048 + k0 + loff2k, aT + c * 512);
    }
#pragma unroll
    for (int it = 0; it < 4; ++it) {
      int c = w * 4 + it;
      gl_lds16(w2b + (colBase + c * 8) * 2048 + k0 + loff2k, bT + c * 512);
    }
    __syncthreads();
#pragma unroll
    for (int k2 = 0; k2 < 2; ++k2) {
      s16x8 af[4], bfr[4];
      const int bir = k2 * 64 + ((lane >> 4) << 4);
#pragma unroll
      for (int mi = 0; mi < 4; ++mi) {
        int row = wm * 64 + mi * 16 + (lane & 15);
        af[mi] = *(const s16x8*)((unsigned char*)aT + swz(row, bir));
      }
#pragma unroll
      for (int ni = 0; ni < 4; ++ni) {
        int col = wn * 64 + ni * 16 + (lane & 15);
        bfr[ni] = *(const s16x8*)((unsigned char*)bT + swz(col, bir));
      }
#pragma unroll
      for (int mi = 0; mi < 4; ++mi)
#pragma unroll
        for (int ni = 0; ni < 4; ++ni)
          acc[mi][ni] = mfma16(af[mi], bfr[ni], acc[mi][ni]);
    }
    __syncthreads();
  }
#pragma unroll
  for (int mi = 0; mi < 4; ++mi)
#pragma unroll
    for (int ni = 0; ni < 4; ++ni) {
      long gcol = colBase + wn * 64 + ni * 16 + (lane & 15);
      float bias = b2[gcol];
      int row0 = wm * 64 + mi * 16 + ((lane >> 4) << 2);
#pragma unroll
      for (int r = 0; r < 4; ++r) {
        long grow = rowBase + row0 + r;
        ffn2s[grow * 512 + gcol] = acc[mi][ni][r] + bias + agg_f[grow * 512 + gcol];
      }
    }
}

// ---------------------------------------------------------------- K5: LN2
__launch_bounds__(256)
__global__ void ln2_kernel(const float* __restrict__ ffn2s,
                           const float* __restrict__ ln2_g,
                           const float* __restrict__ ln2_b,
                           float* __restrict__ out) {
  const int tb = blockIdx.x;
  const int lane = threadIdx.x & 63, wv = threadIdx.x >> 6;
  const int c0 = lane * 8;
  float4 g0 = *(const float4*)(ln2_g + c0);
  float4 g1 = *(const float4*)(ln2_g + c0 + 4);
  float4 b0 = *(const float4*)(ln2_b + c0);
  float4 b1 = *(const float4*)(ln2_b + c0 + 4);
#pragma unroll
  for (int i = 0; i < 4; ++i) {
    long row = (long)tb * 16 + wv * 4 + i;
    const float* src = ffn2s + row * 512 + c0;
    float4 a = *(const float4*)src;
    float4 c = *(const float4*)(src + 4);
    float sum = a.x + a.y + a.z + a.w + c.x + c.y + c.z + c.w;
    float sq = a.x * a.x + a.y * a.y + a.z * a.z + a.w * a.w +
               c.x * c.x + c.y * c.y + c.z * c.z + c.w * c.w;
#pragma unroll
    for (int off = 1; off < 64; off <<= 1) {
      sum += __shfl_xor(sum, off); sq += __shfl_xor(sq, off);
    }
    float mu = sum * (1.f / 512.f);
    float is = rsqrtf(sq * (1.f / 512.f) - mu * mu + 1e-5f);
    float* dst = out + row * 512 + c0;
    *(float4*)dst = (float4){(a.x - mu) * is * g0.x + b0.x, (a.y - mu) * is * g0.y + b0.y,
                             (a.z - mu) * is * g0.z + b0.z, (a.w - mu) * is * g0.w + b0.w};
    *(float4*)(dst + 4) = (float4){(c.x - mu) * is * g1.x + b1.x, (c.y - mu) * is * g1.y + b1.y,
                                   (c.z - mu) * is * g1.z + b1.z, (c.w - mu) * is * g1.w + b1.w};
  }
}

// ---------------------------------------------------------------- launch
extern "C" void kernel_launch(void* const* d_in, const int* in_sizes, int n_in,
                              void* d_out, int out_size, void* d_ws, size_t ws_size,
                              hipStream_t stream) {
  (void)in_sizes; (void)n_in; (void)out_size;
  const float* x0 = (const float*)d_in[0];
  const float* x1 = (const float*)d_in[1];
  const float* x2 = (const float*)d_in[2];
  const float* x3 = (const float*)d_in[3];
  const float* in_w = (const float*)d_in[4];
  const float* in_b = (const float*)d_in[5];
  const float* out_w = (const float*)d_in[6];
  const float* out_b = (const float*)d_in[7];
  const float* ln1_g = (const float*)d_in[8];
  const float* ln1_b = (const float*)d_in[9];
  const float* w1 = (const float*)d_in[10];
  const float* b1 = (const float*)d_in[11];
  const float* w2 = (const float*)d_in[12];
  const float* b2 = (const float*)d_in[13];
  const float* ln2_g = (const float*)d_in[14];
  const float* ln2_b = (const float*)d_in[15];
  float* out = (float*)d_out;

  unsigned char* ws = (unsigned char*)d_ws;
  if (ws_size < 190840832u) return;
  unsigned short* wqkv_b = (unsigned short*)(ws + 0);
  unsigned short* wout_b = (unsigned short*)(ws + 1572864);
  unsigned short* w1_b = (unsigned short*)(ws + 2097152);
  unsigned short* w2_b = (unsigned short*)(ws + 4194304);
  float* ffn2s = (float*)(ws + 6291456);
  unsigned short* o_buf = (unsigned short*)(ws + 73400320);
  float* agg_f = (float*)(ws + 140509184);
  unsigned short* agg_b = (unsigned short*)(ws + 174063616);
  unsigned short* hidden = o_buf;  // overlay: o dead after K2

  pack_w_kernel<<<1024, 256, 0, stream>>>(in_w, out_w, w1, w2,
                                          wqkv_b, wout_b, w1_b, w2_b);
  qkv_attn_kernel<<<4096, 256, 0, stream>>>(x0, x1, x2, x3, wqkv_b, in_b, o_buf);
  outproj_ln1_kernel<<<2048, 256, 0, stream>>>(o_buf, wout_b, out_b, x0, x1, x2, x3,
                                               ln1_g, ln1_b, agg_f, agg_b);
  ffn1_kernel<<<2048, 256, 0, stream>>>(agg_b, w1_b, b1, hidden);
  ffn2_kernel<<<512, 256, 0, stream>>>(hidden, w2_b, b2, agg_f, ffn2s);
  ln2_kernel<<<1024, 256, 0, stream>>>(ffn2s, ln2_g, ln2_b, out);
}

// Round 15
// 394.554 us; speedup vs baseline: 1.1775x; 1.1775x over previous
//
#include <hip/hip_runtime.h>
#include <hip/hip_bf16.h>

// MultimodalFusion: B*H=16384 tokens, NMOD=4, M=512, NH=8, DH=64, FFN=2048.
// R15 = R13 (best measured, 394.6us): pack(x4+weights) -> K1 qkv+MFMA-attn
// (gl_lds staging, XCD swizzle, 49KB LDS) -> K2 outproj+LN1+agg (fused) ->
// K3 ffn1+gelu (gl_lds 128^2) -> K4 ffn2 GEMM -> K5 LN2.
//
// ws layout (bytes):
//   wqkv_b  @ 0          1,572,864   (1536x512 bf16)
//   wout_b  @ 1572864      524,288   (512x512)
//   w1_b    @ 2097152    2,097,152   (2048x512)
//   w2_b    @ 4194304    2,097,152   (512x2048)
//   x4      @ 6291456   67,108,864   (bf16)  [ffn2s f32 overlays after K2]
//   o_buf   @ 73400320  67,108,864   (bf16)  [hidden overlays after K2]
//   agg_f   @ 140509184 33,554,432   (16384x512 fp32)
//   agg_b   @ 174063616 16,777,216   (16384x512 bf16)

typedef __attribute__((ext_vector_type(8))) short s16x8;
typedef __attribute__((ext_vector_type(4))) float f32x4;

__device__ __forceinline__ unsigned short f2bf(float f) {
  unsigned int u = __float_as_uint(f);
  u += 0x7fffu + ((u >> 16) & 1u);
  return (unsigned short)(u >> 16);
}
__device__ __forceinline__ float bf2f(unsigned short s) {
  return __uint_as_float(((unsigned int)s) << 16);
}
__device__ __forceinline__ f32x4 mfma16(s16x8 a, s16x8 b, f32x4 c) {
  return __builtin_amdgcn_mfma_f32_16x16x32_bf16(a, b, c, 0, 0, 0);
}
// byte offset into a [rows][64] bf16 tile (128B rows), XOR-swizzled 16B granules
__device__ __forceinline__ int swz(int row, int bir) {
  return row * 128 + ((((row) & 7) << 4) ^ bir);
}
// scalar u16 element in a [rows][64] swizzled tile
__device__ __forceinline__ int qkswz(int row, int c) {
  return row * 128 + ((((c >> 3) ^ (row & 7)) << 4)) + (c & 7) * 2;
}
// Vt [64][128] u16: row=d (256B), col=token-row; XOR key d&7
__device__ __forceinline__ int vtswz(int d, int row) {
  return d * 256 + ((((row >> 3) ^ (d & 7)) << 4)) + (row & 7) * 2;
}
// Pw [128][32] u16: 64B rows; XOR key row&3
__device__ __forceinline__ int pwswz(int row, int c) {
  return row * 64 + ((((c >> 3) ^ (row & 3)) << 4)) + (c & 7) * 2;
}
// byte offset into a [rows][512] bf16 vt tile (1024B rows), XOR-swizzled
__device__ __forceinline__ int vtoff(int r, int c) {
  return r * 1024 + ((c * 2) ^ ((r & 7) << 4));
}
// async global->LDS 16B per lane; dest = wave-uniform base + lane*16
__device__ __forceinline__ void gl_lds16(const void* g, void* l) {
  __builtin_amdgcn_global_load_lds(
      (const __attribute__((address_space(1))) unsigned int*)g,
      (__attribute__((address_space(3))) unsigned int*)l, 16, 0, 0);
}

// ---------------------------------------------------------------- pack
__global__ void pack_kernel(const float* __restrict__ wqkv, const float* __restrict__ wout,
                            const float* __restrict__ w1, const float* __restrict__ w2,
                            const float* __restrict__ x0, const float* __restrict__ x1,
                            const float* __restrict__ x2, const float* __restrict__ x3,
                            unsigned short* __restrict__ o_wqkv, unsigned short* __restrict__ o_wout,
                            unsigned short* __restrict__ o_w1, unsigned short* __restrict__ o_w2,
                            unsigned short* __restrict__ o_x4) {
  const long c0 = 196608, c1 = 262144, c2 = 524288, c3 = 786432, c4 = 9175040;
  for (long v = (long)blockIdx.x * blockDim.x + threadIdx.x; v < c4;
       v += (long)gridDim.x * blockDim.x) {
    const float* src;
    unsigned short* dst;
    if (v < c0) { src = wqkv + v * 4; dst = o_wqkv + v * 4; }
    else if (v < c1) { long u = v - c0; src = wout + u * 4; dst = o_wout + u * 4; }
    else if (v < c2) { long u = v - c1; src = w1 + u * 4; dst = o_w1 + u * 4; }
    else if (v < c3) { long u = v - c2; src = w2 + u * 4; dst = o_w2 + u * 4; }
    else {
      long u = v - c3; long e = u * 4; long r = e >> 9; int i = (int)(e & 511);
      int s = (int)(r & 3); long n = r >> 2;
      const float* xs = (s == 0) ? x0 : (s == 1) ? x1 : (s == 2) ? x2 : x3;
      src = xs + n * 512 + i; dst = o_x4 + e;
    }
    float4 f = *reinterpret_cast<const float4*>(src);
    ushort4 hb;
    hb.x = f2bf(f.x); hb.y = f2bf(f.y); hb.z = f2bf(f.z); hb.w = f2bf(f.w);
    *reinterpret_cast<ushort4*>(dst) = hb;
  }
}

// ---------------------------------------------------------------- K1: qkv + attention
// flat grid 4096; XCD-bijective swizzle (8 head-blocks of a token-block -> same XCD).
// gl_lds staging: linear LDS dest (8-row chunks), pre-swizzled per-lane source.
// LDS 49152: @0 aT/Qs/Pw, @16384 bT/Ks/outT, @32768 Vt.
__launch_bounds__(256, 3)
__global__ void qkv_attn_kernel(const unsigned short* __restrict__ x4,
                                const unsigned short* __restrict__ wqkv,
                                const float* __restrict__ in_b,
                                unsigned short* __restrict__ o_out) {
  const int wg = blockIdx.x;
  const int slot = wg >> 3, xcd = wg & 7;
  const int tb = ((slot >> 3) << 3) | xcd;  // [0,512)
  const int h = slot & 7;                   // [0,8)
  const int tid = threadIdx.x, lane = tid & 63, w = tid >> 6;
  const int wm = w >> 1, wn = w & 1;

  __shared__ __align__(16) unsigned char smem[49152];
  unsigned short* aT = (unsigned short*)smem;            // [128][64] staging
  unsigned short* bT = (unsigned short*)(smem + 16384);  // [192][64] staging
  unsigned short* Qs = (unsigned short*)smem;            // [128][64] (over aT)
  unsigned short* Ks = (unsigned short*)(smem + 16384);  // [128][64] (over bT head)
  unsigned short* Vt = (unsigned short*)(smem + 32768);  // [64][128] (over bT tail)
  unsigned short* Pw = (unsigned short*)smem;            // [128][32] (over Qs, after sacc)
  unsigned short* outT = (unsigned short*)(smem + 16384);// [128][64] qkswz (over Ks, after sacc)

  f32x4 acc[4][6];
#pragma unroll
  for (int i = 0; i < 4; ++i)
#pragma unroll
    for (int j = 0; j < 6; ++j) acc[i][j] = (f32x4){0.f, 0.f, 0.f, 0.f};

  const long rowBase = (long)tb * 128;
  const int loff = ((lane >> 3) * 512) + (((lane & 7) ^ (lane >> 3)) * 8);

  for (int kk = 0; kk < 8; ++kk) {
    const int k0 = kk * 64;
#pragma unroll
    for (int it = 0; it < 4; ++it) {  // A: 16 chunks of 8 rows
      int c = w * 4 + it;
      gl_lds16(x4 + (rowBase + c * 8) * 512 + k0 + loff, aT + c * 512);
    }
#pragma unroll
    for (int it = 0; it < 6; ++it) {  // B: 24 chunks of 8 weight rows
      int c = w * 6 + it;
      int bc0 = c * 8;
      int wb = (bc0 < 64) ? (h * 64 + bc0)
             : (bc0 < 128) ? (512 + h * 64 + (bc0 - 64))
                           : (1024 + h * 64 + (bc0 - 128));
      gl_lds16(wqkv + (long)wb * 512 + k0 + loff, bT + c * 512);
    }
    __syncthreads();
#pragma unroll
    for (int k2 = 0; k2 < 2; ++k2) {
      s16x8 af[4], bfr[6];
      const int bir = k2 * 64 + ((lane >> 4) << 4);
#pragma unroll
      for (int mi = 0; mi < 4; ++mi) {
        int row = wm * 64 + mi * 16 + (lane & 15);
        af[mi] = *(const s16x8*)((unsigned char*)aT + swz(row, bir));
      }
#pragma unroll
      for (int ni = 0; ni < 6; ++ni) {
        int col = wn * 96 + ni * 16 + (lane & 15);
        bfr[ni] = *(const s16x8*)((unsigned char*)bT + swz(col, bir));
      }
#pragma unroll
      for (int mi = 0; mi < 4; ++mi)
#pragma unroll
        for (int ni = 0; ni < 6; ++ni)
          acc[mi][ni] = mfma16(af[mi], bfr[ni], acc[mi][ni]);
    }
    __syncthreads();
  }

  // epilogue: acc(+bias) -> Qs / Ks / Vt (bf16).  D: col=lane&15, row=(lane>>4)*4+r
#pragma unroll
  for (int mi = 0; mi < 4; ++mi)
#pragma unroll
    for (int ni = 0; ni < 6; ++ni) {
      int col = wn * 96 + ni * 16 + (lane & 15);
      int wb = (col < 64) ? (h * 64 + col)
             : (col < 128) ? (512 + h * 64 + (col - 64))
                           : (1024 + h * 64 + (col - 128));
      float bias = in_b[wb];
      int row0 = wm * 64 + mi * 16 + ((lane >> 4) << 2);
#pragma unroll
      for (int r = 0; r < 4; ++r) {
        int row = row0 + r;
        unsigned short hv = f2bf(acc[mi][ni][r] + bias);
        if (col < 64)
          *(unsigned short*)((unsigned char*)Qs + qkswz(row, col)) = hv;
        else if (col < 128)
          *(unsigned short*)((unsigned char*)Ks + qkswz(row, col - 64)) = hv;
        else
          *(unsigned short*)((unsigned char*)Vt + vtswz(col - 128, row)) = hv;
      }
    }
  __syncthreads();

  // S = Q.K^T per 16-row tile (2 tiles/wave), MFMA
  f32x4 sacc[2];
#pragma unroll
  for (int i2 = 0; i2 < 2; ++i2) {
    int ti = w * 2 + i2;
    int qrow = ti * 16 + (lane & 15);
    int bir = (lane >> 4) << 4;
    s16x8 qa0 = *(const s16x8*)((unsigned char*)Qs + swz(qrow, bir));
    s16x8 qa1 = *(const s16x8*)((unsigned char*)Qs + swz(qrow, 64 + bir));
    s16x8 ka0 = *(const s16x8*)((unsigned char*)Ks + swz(qrow, bir));
    s16x8 ka1 = *(const s16x8*)((unsigned char*)Ks + swz(qrow, 64 + bir));
    f32x4 s = (f32x4){0.f, 0.f, 0.f, 0.f};
    s = mfma16(qa0, ka0, s);
    s = mfma16(qa1, ka1, s);
    sacc[i2] = s;
  }
  __syncthreads();  // Qs/Ks dead; Pw and outT may now overlay them
  {
    s16x8 z = (s16x8){0, 0, 0, 0, 0, 0, 0, 0};
    ((s16x8*)Pw)[tid] = z;
    ((s16x8*)Pw)[tid + 256] = z;
  }
  __syncthreads();

  // softmax: lane holds S[qrow=(ti*16+(l>>4)*4+r)][kcol=ti*16+(l&15)].
  const bool rel = ((lane & 15) >> 2) == (lane >> 4);
#pragma unroll
  for (int i2 = 0; i2 < 2; ++i2) {
    int ti = w * 2 + i2;
#pragma unroll
    for (int r = 0; r < 4; ++r) {
      float sc = sacc[i2][r] * 0.125f;
      float m = fmaxf(sc, __shfl_xor(sc, 1));
      m = fmaxf(m, __shfl_xor(m, 2));
      float e = __expf(sc - m);
      float su = e + __shfl_xor(e, 1);
      su = su + __shfl_xor(su, 2);
      float p = e / su;
      if (rel) {
        int row = ti * 16 + ((lane >> 4) << 2) + r;
        int cl = (((row >> 2) & 7) << 2) + (lane & 3);
        *(unsigned short*)((unsigned char*)Pw + pwswz(row, cl)) = f2bf(p);
      }
    }
  }
  __syncthreads();

  // PV per tile: o(16x64) = Pw(16x32 window) x Vt; 4 MFMA, write outT
#pragma unroll
  for (int i2 = 0; i2 < 2; ++i2) {
    int ti = w * 2 + i2;
    int arow = ti * 16 + (lane & 15);
    s16x8 pa = *(const s16x8*)((unsigned char*)Pw + arow * 64 +
                               ((((lane >> 4) ^ (arow & 3)) << 4)));
    f32x4 pv4[4];
#pragma unroll
    for (int n = 0; n < 4; ++n) {
      int d = n * 16 + (lane & 15);
      int gran = ((ti >> 1) << 2) + (lane >> 4);
      s16x8 vb = *(const s16x8*)((unsigned char*)Vt + d * 256 +
                                 (((gran ^ (d & 7)) << 4)));
      pv4[n] = mfma16(pa, vb, (f32x4){0.f, 0.f, 0.f, 0.f});
    }
#pragma unroll
    for (int n = 0; n < 4; ++n) {
      int d = n * 16 + (lane & 15);
      int row0 = ti * 16 + ((lane >> 4) << 2);
#pragma unroll
      for (int r = 0; r < 4; ++r)
        *(unsigned short*)((unsigned char*)outT + qkswz(row0 + r, d)) =
            f2bf(pv4[n][r]);
    }
  }
  __syncthreads();
#pragma unroll
  for (int j = 0; j < 4; ++j) {
    int c = j * 256 + tid;
    int row = c >> 3, ch = c & 7;
    s16x8 v = *(const s16x8*)((unsigned char*)outT + qkswz(row, ch * 8));
    *(s16x8*)(o_out + (rowBase + row) * 512 + h * 64 + ch * 8) = v;
  }
}

// ---------------------------------------------------------------- K2: out_proj + LN1 + agg
// grid 2048 (8 tokens = 32 X-rows each). Residual F from bf16 x4 (contiguous).
__launch_bounds__(256)
__global__ void outproj_ln1_kernel(const unsigned short* __restrict__ o_in,
                                   const unsigned short* __restrict__ wout,
                                   const float* __restrict__ out_b,
                                   const unsigned short* __restrict__ x4,
                                   const float* __restrict__ ln1_g, const float* __restrict__ ln1_b,
                                   float* __restrict__ agg_f, unsigned short* __restrict__ agg_b) {
  const int tb = blockIdx.x;
  const int tid = threadIdx.x, lane = tid & 63, w = tid >> 6;
  __shared__ __align__(16) unsigned char smem[53504];
  unsigned short* vt = (unsigned short*)smem;            // [32][512] bf16, XOR-swizzled
  unsigned short* aT = (unsigned short*)(smem + 32768);  // [32][64]
  unsigned short* bT = (unsigned short*)(smem + 36864);  // [128][64]
  float* stats = (float*)(smem + 53248);                 // [32][2]
  const long rowBase = (long)tb * 32;

  for (int ns = 0; ns < 4; ++ns) {
    f32x4 acc[2][2];
#pragma unroll
    for (int i = 0; i < 2; ++i)
#pragma unroll
      for (int j = 0; j < 2; ++j) acc[i][j] = (f32x4){0.f, 0.f, 0.f, 0.f};
    for (int kk = 0; kk < 8; ++kk) {
      const int k0 = kk * 64;
      {
        int lr = tid >> 3, c8 = tid & 7;
        s16x8 v = *(const s16x8*)(o_in + (rowBase + lr) * 512 + k0 + c8 * 8);
        *(s16x8*)((unsigned char*)aT + swz(lr, c8 * 16)) = v;
      }
#pragma unroll
      for (int it = 0; it < 4; ++it) {
        int cid = tid + it * 256, bc = cid >> 3, c8 = cid & 7;
        s16x8 v = *(const s16x8*)(wout + (long)(ns * 128 + bc) * 512 + k0 + c8 * 8);
        *(s16x8*)((unsigned char*)bT + swz(bc, c8 * 16)) = v;
      }
      __syncthreads();
#pragma unroll
      for (int k2 = 0; k2 < 2; ++k2) {
        s16x8 af[2], bfr[2];
        const int bir = k2 * 64 + ((lane >> 4) << 4);
#pragma unroll
        for (int mi = 0; mi < 2; ++mi) {
          int row = mi * 16 + (lane & 15);
          af[mi] = *(const s16x8*)((unsigned char*)aT + swz(row, bir));
        }
#pragma unroll
        for (int ni = 0; ni < 2; ++ni) {
          int col = w * 32 + ni * 16 + (lane & 15);
          bfr[ni] = *(const s16x8*)((unsigned char*)bT + swz(col, bir));
        }
#pragma unroll
        for (int mi = 0; mi < 2; ++mi)
#pragma unroll
          for (int ni = 0; ni < 2; ++ni)
            acc[mi][ni] = mfma16(af[mi], bfr[ni], acc[mi][ni]);
      }
      __syncthreads();
    }
#pragma unroll
    for (int mi = 0; mi < 2; ++mi)
#pragma unroll
      for (int ni = 0; ni < 2; ++ni) {
        int gcol = ns * 128 + w * 32 + ni * 16 + (lane & 15);
        float bias = out_b[gcol];
        int row0 = mi * 16 + ((lane >> 4) << 2);
#pragma unroll
        for (int r = 0; r < 4; ++r) {
          int rr = row0 + r;
          float F = bf2f(x4[(rowBase + rr) * 512 + gcol]);
          *(unsigned short*)((unsigned char*)vt + vtoff(rr, gcol)) =
              f2bf(acc[mi][ni][r] + bias + F);
        }
      }
  }
  __syncthreads();
  {  // per-row LN1 stats: one wave per 8 rows
    int wv = tid >> 6, ln = tid & 63;
    for (int i = 0; i < 8; ++i) {
      int r = wv * 8 + i;
      s16x8 v8 = *(const s16x8*)((unsigned char*)vt + vtoff(r, ln * 8));
      float sum = 0.f, sq = 0.f;
#pragma unroll
      for (int d = 0; d < 8; ++d) {
        float v = bf2f((unsigned short)v8[d]);
        sum += v; sq += v * v;
      }
#pragma unroll
      for (int off = 1; off < 64; off <<= 1) {
        sum += __shfl_xor(sum, off); sq += __shfl_xor(sq, off);
      }
      if (ln == 0) {
        float mu = sum * (1.f / 512.f);
        float var = sq * (1.f / 512.f) - mu * mu;
        stats[r * 2] = mu;
        stats[r * 2 + 1] = rsqrtf(var + 1e-5f);
      }
    }
  }
  __syncthreads();
  for (int it = 0; it < 2; ++it) {  // agg over modalities, 8-col chunks
    int ci = tid + it * 256;
    int tok = ci >> 6, c0 = (ci & 63) * 8;
    long gtok = (long)tb * 8 + tok;
    float a[8] = {0.f, 0.f, 0.f, 0.f, 0.f, 0.f, 0.f, 0.f};
#pragma unroll
    for (int s = 0; s < 4; ++s) {
      int r = tok * 4 + s;
      s16x8 v8 = *(const s16x8*)((unsigned char*)vt + vtoff(r, c0));
      float mu = stats[r * 2], is = stats[r * 2 + 1];
#pragma unroll
      for (int d = 0; d < 8; ++d) a[d] += (bf2f((unsigned short)v8[d]) - mu) * is;
    }
    float4 g0 = *(const float4*)(ln1_g + c0);
    float4 g1 = *(const float4*)(ln1_g + c0 + 4);
    float4 b0 = *(const float4*)(ln1_b + c0);
    float4 b1 = *(const float4*)(ln1_b + c0 + 4);
    float ov[8];
    ov[0] = g0.x * a[0] + 4.f * b0.x; ov[1] = g0.y * a[1] + 4.f * b0.y;
    ov[2] = g0.z * a[2] + 4.f * b0.z; ov[3] = g0.w * a[3] + 4.f * b0.w;
    ov[4] = g1.x * a[4] + 4.f * b1.x; ov[5] = g1.y * a[5] + 4.f * b1.y;
    ov[6] = g1.z * a[6] + 4.f * b1.z; ov[7] = g1.w * a[7] + 4.f * b1.w;
    *(float4*)(agg_f + gtok * 512 + c0) = (float4){ov[0], ov[1], ov[2], ov[3]};
    *(float4*)(agg_f + gtok * 512 + c0 + 4) = (float4){ov[4], ov[5], ov[6], ov[7]};
    s16x8 ab;
#pragma unroll
    for (int d = 0; d < 8; ++d) ab[d] = (short)f2bf(ov[d]);
    *(s16x8*)(agg_b + gtok * 512 + c0) = ab;
  }
}

// ---------------------------------------------------------------- K3: ffn1 + gelu
__launch_bounds__(256)
__global__ void ffn1_kernel(const unsigned short* __restrict__ aggb,
                            const unsigned short* __restrict__ w1b,
                            const float* __restrict__ b1,
                            unsigned short* __restrict__ hidden) {
  const int wg = blockIdx.x;
  const int slot = wg >> 3, xcd = wg & 7;
  const int by = ((slot >> 4) << 3) | xcd;  // [0,128) row-tile
  const int bx = slot & 15;                 // [0,16)  col-tile
  const int tid = threadIdx.x, lane = tid & 63, w = tid >> 6;
  const int wm = w >> 1, wn = w & 1;
  __shared__ __align__(16) unsigned char smem[32768];
  unsigned short* aT = (unsigned short*)smem;            // [128][64]
  unsigned short* bT = (unsigned short*)(smem + 16384);  // [128][64]
  f32x4 acc[4][4];
#pragma unroll
  for (int i = 0; i < 4; ++i)
#pragma unroll
    for (int j = 0; j < 4; ++j) acc[i][j] = (f32x4){0.f, 0.f, 0.f, 0.f};
  const long rowBase = (long)by * 128;
  const long colBase = (long)bx * 128;
  const int loff = ((lane >> 3) * 512) + (((lane & 7) ^ (lane >> 3)) * 8);
  for (int kk = 0; kk < 8; ++kk) {
    const int k0 = kk * 64;
#pragma unroll
    for (int it = 0; it < 4; ++it) {
      int c = w * 4 + it;
      gl_lds16(aggb + (rowBase + c * 8) * 512 + k0 + loff, aT + c * 512);
    }
#pragma unroll
    for (int it = 0; it < 4; ++it) {
      int c = w * 4 + it;
      gl_lds16(w1b + (colBase + c * 8) * 512 + k0 + loff, bT + c * 512);
    }
    __syncthreads();
#pragma unroll
    for (int k2 = 0; k2 < 2; ++k2) {
      s16x8 af[4], bfr[4];
      const int bir = k2 * 64 + ((lane >> 4) << 4);
#pragma unroll
      for (int mi = 0; mi < 4; ++mi) {
        int row = wm * 64 + mi * 16 + (lane & 15);
        af[mi] = *(const s16x8*)((unsigned char*)aT + swz(row, bir));
      }
#pragma unroll
      for (int ni = 0; ni < 4; ++ni) {
        int col = wn * 64 + ni * 16 + (lane & 15);
        bfr[ni] = *(const s16x8*)((unsigned char*)bT + swz(col, bir));
      }
#pragma unroll
      for (int mi = 0; mi < 4; ++mi)
#pragma unroll
        for (int ni = 0; ni < 4; ++ni)
          acc[mi][ni] = mfma16(af[mi], bfr[ni], acc[mi][ni]);
    }
    __syncthreads();
  }
#pragma unroll
  for (int mi = 0; mi < 4; ++mi)
#pragma unroll
    for (int ni = 0; ni < 4; ++ni) {
      long gcol = colBase + wn * 64 + ni * 16 + (lane & 15);
      float bias = b1[gcol];
      int row0 = wm * 64 + mi * 16 + ((lane >> 4) << 2);
#pragma unroll
      for (int r = 0; r < 4; ++r) {
        float x = acc[mi][ni][r] + bias;
        float g = 0.5f * x * (1.f + erff(x * 0.70710678118f));
        hidden[(rowBase + row0 + r) * 2048 + gcol] = f2bf(g);
      }
    }
}

// ---------------------------------------------------------------- K4: ffn2 GEMM
__launch_bounds__(256)
__global__ void ffn2_kernel(const unsigned short* __restrict__ hidden,
                            const unsigned short* __restrict__ w2b,
                            const float* __restrict__ b2,
                            const float* __restrict__ agg_f,
                            float* __restrict__ ffn2s) {
  const int wg = blockIdx.x;
  const int slot = wg >> 3, xcd = wg & 7;
  const int by = ((slot >> 2) << 3) | xcd;  // [0,128) row-tile
  const int bx = slot & 3;                  // [0,4)   col-tile
  const int tid = threadIdx.x, lane = tid & 63, w = tid >> 6;
  const int wm = w >> 1, wn = w & 1;
  __shared__ __align__(16) unsigned char smem[32768];
  unsigned short* aT = (unsigned short*)smem;            // [128][64]
  unsigned short* bT = (unsigned short*)(smem + 16384);  // [128][64]
  f32x4 acc[4][4];
#pragma unroll
  for (int i = 0; i < 4; ++i)
#pragma unroll
    for (int j = 0; j < 4; ++j) acc[i][j] = (f32x4){0.f, 0.f, 0.f, 0.f};
  const long rowBase = (long)by * 128;
  const long colBase = (long)bx * 128;
  const int loff2k = ((lane >> 3) * 2048) + (((lane & 7) ^ (lane >> 3)) * 8);
  for (int kk = 0; kk < 32; ++kk) {
    const int k0 = kk * 64;
#pragma unroll
    for (int it = 0; it < 4; ++it) {
      int c = w * 4 + it;
      gl_lds16(hidden + (rowBase + c * 8) * 2048 + k0 + loff2k, aT + c * 512);
    }
#pragma unroll
    for (int it = 0; it < 4; ++it) {
      int c = w * 4 + it;
      gl_lds16(w2b + (colBase + c * 8) * 2048 + k0 + loff2k, bT + c * 512);
    }
    __syncthreads();
#pragma unroll
    for (int k2 = 0; k2 < 2; ++k2) {
      s16x8 af[4], bfr[4];
      const int bir = k2 * 64 + ((lane >> 4) << 4);
#pragma unroll
      for (int mi = 0; mi < 4; ++mi) {
        int row = wm * 64 + mi * 16 + (lane & 15);
        af[mi] = *(const s16x8*)((unsigned char*)aT + swz(row, bir));
      }
#pragma unroll
      for (int ni = 0; ni < 4; ++ni) {
        int col = wn * 64 + ni * 16 + (lane & 15);
        bfr[ni] = *(const s16x8*)((unsigned char*)bT + swz(col, bir));
      }
#pragma unroll
      for (int mi = 0; mi < 4; ++mi)
#pragma unroll
        for (int ni = 0; ni < 4; ++ni)
          acc[mi][ni] = mfma16(af[mi], bfr[ni], acc[mi][ni]);
    }
    __syncthreads();
  }
#pragma unroll
  for (int mi = 0; mi < 4; ++mi)
#pragma unroll
    for (int ni = 0; ni < 4; ++ni) {
      long gcol = colBase + wn * 64 + ni * 16 + (lane & 15);
      float bias = b2[gcol];
      int row0 = wm * 64 + mi * 16 + ((lane >> 4) << 2);
#pragma unroll
      for (int r = 0; r < 4; ++r) {
        long grow = rowBase + row0 + r;
        ffn2s[grow * 512 + gcol] = acc[mi][ni][r] + bias + agg_f[grow * 512 + gcol];
      }
    }
}

// ---------------------------------------------------------------- K5: LN2
__launch_bounds__(256)
__global__ void ln2_kernel(const float* __restrict__ ffn2s,
                           const float* __restrict__ ln2_g,
                           const float* __restrict__ ln2_b,
                           float* __restrict__ out) {
  const int tb = blockIdx.x;
  const int lane = threadIdx.x & 63, wv = threadIdx.x >> 6;
  const int c0 = lane * 8;
  float4 g0 = *(const float4*)(ln2_g + c0);
  float4 g1 = *(const float4*)(ln2_g + c0 + 4);
  float4 b0 = *(const float4*)(ln2_b + c0);
  float4 b1 = *(const float4*)(ln2_b + c0 + 4);
#pragma unroll
  for (int i = 0; i < 4; ++i) {
    long row = (long)tb * 16 + wv * 4 + i;
    const float* src = ffn2s + row * 512 + c0;
    float4 a = *(const float4*)src;
    float4 c = *(const float4*)(src + 4);
    float sum = a.x + a.y + a.z + a.w + c.x + c.y + c.z + c.w;
    float sq = a.x * a.x + a.y * a.y + a.z * a.z + a.w * a.w +
               c.x * c.x + c.y * c.y + c.z * c.z + c.w * c.w;
#pragma unroll
    for (int off = 1; off < 64; off <<= 1) {
      sum += __shfl_xor(sum, off); sq += __shfl_xor(sq, off);
    }
    float mu = sum * (1.f / 512.f);
    float is = rsqrtf(sq * (1.f / 512.f) - mu * mu + 1e-5f);
    float* dst = out + row * 512 + c0;
    *(float4*)dst = (float4){(a.x - mu) * is * g0.x + b0.x, (a.y - mu) * is * g0.y + b0.y,
                             (a.z - mu) * is * g0.z + b0.z, (a.w - mu) * is * g0.w + b0.w};
    *(float4*)(dst + 4) = (float4){(c.x - mu) * is * g1.x + b1.x, (c.y - mu) * is * g1.y + b1.y,
                                   (c.z - mu) * is * g1.z + b1.z, (c.w - mu) * is * g1.w + b1.w};
  }
}

// ---------------------------------------------------------------- launch
extern "C" void kernel_launch(void* const* d_in, const int* in_sizes, int n_in,
                              void* d_out, int out_size, void* d_ws, size_t ws_size,
                              hipStream_t stream) {
  (void)in_sizes; (void)n_in; (void)out_size;
  const float* x0 = (const float*)d_in[0];
  const float* x1 = (const float*)d_in[1];
  const float* x2 = (const float*)d_in[2];
  const float* x3 = (const float*)d_in[3];
  const float* in_w = (const float*)d_in[4];
  const float* in_b = (const float*)d_in[5];
  const float* out_w = (const float*)d_in[6];
  const float* out_b = (const float*)d_in[7];
  const float* ln1_g = (const float*)d_in[8];
  const float* ln1_b = (const float*)d_in[9];
  const float* w1 = (const float*)d_in[10];
  const float* b1 = (const float*)d_in[11];
  const float* w2 = (const float*)d_in[12];
  const float* b2 = (const float*)d_in[13];
  const float* ln2_g = (const float*)d_in[14];
  const float* ln2_b = (const float*)d_in[15];
  float* out = (float*)d_out;

  unsigned char* ws = (unsigned char*)d_ws;
  if (ws_size < 190840832u) return;
  unsigned short* wqkv_b = (unsigned short*)(ws + 0);
  unsigned short* wout_b = (unsigned short*)(ws + 1572864);
  unsigned short* w1_b = (unsigned short*)(ws + 2097152);
  unsigned short* w2_b = (unsigned short*)(ws + 4194304);
  unsigned short* x4 = (unsigned short*)(ws + 6291456);
  unsigned short* o_buf = (unsigned short*)(ws + 73400320);
  float* agg_f = (float*)(ws + 140509184);
  unsigned short* agg_b = (unsigned short*)(ws + 174063616);
  unsigned short* hidden = o_buf;        // overlay: o dead after K2
  float* ffn2s = (float*)(ws + 6291456); // overlay: x4 dead after K2

  pack_kernel<<<2048, 256, 0, stream>>>(in_w, out_w, w1, w2, x0, x1, x2, x3,
                                        wqkv_b, wout_b, w1_b, w2_b, x4);
  qkv_attn_kernel<<<4096, 256, 0, stream>>>(x4, wqkv_b, in_b, o_buf);
  outproj_ln1_kernel<<<2048, 256, 0, stream>>>(o_buf, wout_b, out_b, x4,
                                               ln1_g, ln1_b, agg_f, agg_b);
  ffn1_kernel<<<2048, 256, 0, stream>>>(agg_b, w1_b, b1, hidden);
  ffn2_kernel<<<512, 256, 0, stream>>>(hidden, w2_b, b2, agg_f, ffn2s);
  ln2_kernel<<<1024, 256, 0, stream>>>(ffn2s, ln2_g, ln2_b, out);
}